// Round 5
// baseline (180.113 us; speedup 1.0000x reference)
//
#include <hip/hip_runtime.h>

#define NN 4096
#define DIN 512
#define DOUT 128
#define NH 4
#define LOG2E 1.44269504088896340736f

typedef __bf16 bf16x8 __attribute__((ext_vector_type(8)));
typedef float f32x4 __attribute__((ext_vector_type(4)));
typedef float f32x16 __attribute__((ext_vector_type(16)));
typedef unsigned short u16;
typedef unsigned int u32;
typedef unsigned long long u64;
typedef u16 u16x8 __attribute__((ext_vector_type(8)));
typedef u16 u16x4 __attribute__((ext_vector_type(4)));

static __device__ __forceinline__ u16 f2bf(float f) {
  __bf16 h = (__bf16)f;
  return __builtin_bit_cast(u16, h);
}

// async global->LDS, 16B/lane; dest = wave-uniform base + lane*16
static __device__ __forceinline__ void gl_lds16(const void* g, void* l) {
  __builtin_amdgcn_global_load_lds(
      (const __attribute__((address_space(1))) unsigned int*)g,
      (__attribute__((address_space(3))) unsigned int*)l, 16, 0, 0);
}

// ------- Kernel 0: pack adj into bits (ballot, coalesced) + W^T hi/lo -------
__global__ __launch_bounds__(256) void pack_prep(const float* __restrict__ adj,
                                                 u64* __restrict__ adjW,
                                                 const float* __restrict__ W,
                                                 u16* __restrict__ wthi,
                                                 u16* __restrict__ wtlo) {
  const int b = blockIdx.x;
  const int t = threadIdx.x;
  if (b < 2048) {
    const int wv = t >> 6, lane = t & 63;
    const int gw = b * 4 + wv;          // 8192 waves; 2 waves per row
    const int r = gw >> 1, hf = gw & 1;
    const float* src = adj + (size_t)r * NN + hf * 2048 + lane;
    u64* dstw = adjW + (size_t)r * 64 + hf * 32;
    #pragma unroll 4
    for (int it = 0; it < 32; ++it) {
      const u64 m = __ballot(src[it * 64] != 0.f);
      if (lane == 0) dstw[it] = m;
    }
  } else {
    const int n = b - 2048;
    for (int k = t; k < 512; k += 256) {
      const float w = W[(size_t)k * 128 + n];
      const __bf16 hi = (__bf16)w;
      wthi[(size_t)n * 512 + k] = __builtin_bit_cast(u16, hi);
      wtlo[(size_t)n * 512 + k] = f2bf(w - (float)hi);
    }
  }
}

// ------- Kernel 1: h = x@W (split-bf16 MFMA) -> hTf (fragment order) + exps -
__global__ __launch_bounds__(512, 1) void hcompute(
    const float* __restrict__ x, const u16* __restrict__ wthi,
    const u16* __restrict__ wtlo, const float* __restrict__ alw,
    const float* __restrict__ arw, u16x8* __restrict__ hTf,
    float* __restrict__ elP, float* __restrict__ elp,
    float* __restrict__ erQ, float* __restrict__ erq) {
  __shared__ __align__(16) char pool[147456];
  const int t = threadIdx.x;
  const int i0 = blockIdx.x * 16;
  const int lane = t & 63, w = t >> 6;
  const int l15 = lane & 15, lhi = lane >> 4;

  const int xr = t >> 5, xk = (t & 31) * 4;
  const unsigned x_off =
      ((unsigned)(xr * 256 + xk * 2)) ^ ((unsigned)((xr & 7) << 4));

  f32x4 acc = (f32x4){0.f, 0.f, 0.f, 0.f};

  auto stageW = [&](int kc, int buf) {
    #pragma unroll
    for (int q = 0; q < 4; ++q) {
      const int off = q * 8192 + t * 16;
      const int n = off >> 8;
      const int kb = off & 255;
      const int ksrc = (kb ^ ((n & 7) << 4)) >> 1;
      const size_t so = (size_t)n * 512 + kc * 128 + ksrc;
      gl_lds16(wthi + so, pool + 16384 + buf * 32768 + off);
      gl_lds16(wtlo + so, pool + 81920 + buf * 32768 + off);
    }
  };
  auto writeX = [&](const float4& xv, int buf) {
    u16x4 hi, lo;
    const float* xp = (const float*)&xv;
    #pragma unroll
    for (int j = 0; j < 4; ++j) {
      const __bf16 hb = (__bf16)xp[j];
      hi[j] = __builtin_bit_cast(u16, hb);
      lo[j] = f2bf(xp[j] - (float)hb);
    }
    *(u16x4*)(pool + buf * 4096 + x_off) = hi;
    *(u16x4*)(pool + 8192 + buf * 4096 + x_off) = lo;
  };

  stageW(0, 0);
  {
    float4 xv = *(const float4*)(x + (size_t)(i0 + xr) * DIN + xk);
    writeX(xv, 0);
  }
  float4 xnext;
  for (int kc = 0; kc < 4; ++kc) {
    const int cur = kc & 1;
    __syncthreads();
    const bool more = (kc < 3);
    if (more) {
      stageW(kc + 1, cur ^ 1);
      xnext = *(const float4*)(x + (size_t)(i0 + xr) * DIN + (kc + 1) * 128 + xk);
    }
    #pragma unroll
    for (int ks = 0; ks < 4; ++ks) {
      const unsigned kbyte = (unsigned)(ks * 64 + lhi * 16);
      const unsigned xoff =
          (unsigned)(l15 * 256) + (kbyte ^ (unsigned)((l15 & 7) << 4));
      const bf16x8 ah = *(const bf16x8*)(pool + cur * 4096 + xoff);
      const bf16x8 al = *(const bf16x8*)(pool + 8192 + cur * 4096 + xoff);
      const int n = w * 16 + l15;
      const unsigned wb =
          (unsigned)(n * 256) + (kbyte ^ (unsigned)((n & 7) << 4));
      const bf16x8 bh = *(const bf16x8*)(pool + 16384 + cur * 32768 + wb);
      const bf16x8 bl = *(const bf16x8*)(pool + 81920 + cur * 32768 + wb);
      acc = __builtin_amdgcn_mfma_f32_16x16x32_bf16(ah, bh, acc, 0, 0, 0);
      acc = __builtin_amdgcn_mfma_f32_16x16x32_bf16(al, bh, acc, 0, 0, 0);
      acc = __builtin_amdgcn_mfma_f32_16x16x32_bf16(ah, bl, acc, 0, 0, 0);
    }
    if (more) writeX(xnext, cur ^ 1);
  }
  __syncthreads();
  float* h_lds = (float*)(pool + 16384);  // [16][132]
  #pragma unroll
  for (int reg = 0; reg < 4; ++reg)
    h_lds[(lhi * 4 + reg) * 132 + w * 16 + l15] = acc[reg];
  __syncthreads();
  // hTf store: fragment order chunk = (jt*16 + ct*4 + kt)*64 + l
  if (t < 256) {
    const int d = t >> 1, c8 = t & 1;
    const int j0 = c8 * 8;
    u16x8 hv;
    #pragma unroll
    for (int q = 0; q < 8; ++q) hv[q] = f2bf(h_lds[(j0 + q) * 132 + d]);
    const int jt = i0 >> 6;
    const int w8 = ((i0 >> 3) & 7) + c8;
    const int kt = w8 >> 1, lb = w8 & 1;
    const int ct = d >> 5;
    const int l = lb * 32 + (d & 31);
    hTf[(size_t)((jt * 16 + ct * 4 + kt) * 64 + l)] = hv;
  }
  // el/er -> exp-precomputed arrays (P=2^(e*log2e)=e^e, p for 0.2 slope)
  if (t < 128) {
    const int r = t >> 3, hh = (t >> 1) & 3, side = t & 1;
    const float* wrow = (side ? arw : alw) + hh * DOUT;
    float s = 0.f;
    for (int d = 0; d < 128; ++d) s += h_lds[r * 132 + d] * wrow[d];
    s *= LOG2E;
    const float e1 = exp2f(s), e2 = exp2f(0.2f * s);
    if (side == 0) {
      elP[(size_t)(i0 + r) * NH + hh] = e1;
      elp[(size_t)(i0 + r) * NH + hh] = e2;
    } else {
      erQ[(size_t)hh * NN + i0 + r] = e1;
      erq[(size_t)hh * NN + i0 + r] = e2;
    }
  }
}

// ------- Kernel 2: fused A-gen(in-reg, exp-free) + PV GEMM, barrier-free ----
// 8 waves = rt(2) x kkg(4); B frags loaded global->reg from fragment-ordered
// hTf; LDS only for epilogue reduction. No main-loop barriers.
__global__ __launch_bounds__(512, 2) void gat_main(
    const unsigned char* __restrict__ adjB, const u16x8* __restrict__ Bf,
    const float* __restrict__ elP, const float* __restrict__ elp,
    const float* __restrict__ erQ, const float* __restrict__ erq,
    const float* __restrict__ bias, float* __restrict__ outp) {
  __shared__ float red[2][4096];
  __shared__ float S_lds[64];
  const int t = threadIdx.x;
  const int i0 = blockIdx.x * 16;
  const int lane = t & 63;
  const int w = t >> 6;
  const int rt = (w >> 2) & 1;
  const int kkg = w & 3;
  const int l31 = lane & 31;
  const int lh = lane >> 5;
  const int il = l31 & 15;
  const int head = rt * 2 + (l31 >> 4);
  if (t < 64) S_lds[t] = 0.f;
  __syncthreads();
  const float Pv = elP[(size_t)(i0 + il) * NH + head];
  const float pv = elp[(size_t)(i0 + il) * NH + head];
  const unsigned char* adjp = adjB + (size_t)(i0 + il) * 512 + kkg * 2 + lh;
  const float* Qp = erQ + (size_t)head * NN + kkg * 16 + lh * 8;
  const float* qp = erq + (size_t)head * NN + kkg * 16 + lh * 8;
  const int fbase = kkg * 64 + lane;  // + jt*1024 + ct*256

  f32x16 acc0, acc1, acc2, acc3, accS;
  #pragma unroll
  for (int q = 0; q < 16; ++q) {
    acc0[q] = 0.f; acc1[q] = 0.f; acc2[q] = 0.f; acc3[q] = 0.f; accS[q] = 0.f;
  }
  u16x8 onesu;
  #pragma unroll
  for (int q = 0; q < 8; ++q) onesu[q] = 0x3F80;  // bf16 1.0
  const bf16x8 onesf = __builtin_bit_cast(bf16x8, onesu);

  auto loadP = [&](int jt, float4& Q0, float4& Q1, float4& q0, float4& q1,
                   u32& ab, u16x8& b0, u16x8& b1, u16x8& b2, u16x8& b3) {
    const float* Qj = Qp + jt * 64;
    const float* qj = qp + jt * 64;
    Q0 = *(const float4*)Qj;
    Q1 = *(const float4*)(Qj + 4);
    q0 = *(const float4*)qj;
    q1 = *(const float4*)(qj + 4);
    ab = adjp[jt * 8];
    const u16x8* fb = Bf + jt * 1024 + fbase;
    b0 = fb[0];
    b1 = fb[256];
    b2 = fb[512];
    b3 = fb[768];
  };
  auto computeP = [&](const float4& Q0, const float4& Q1, const float4& q0,
                      const float4& q1, u32 ab, const u16x8& b0,
                      const u16x8& b1, const u16x8& b2, const u16x8& b3) {
    float Qv[8], qv[8];
    *(float4*)Qv = Q0;
    *(float4*)(Qv + 4) = Q1;
    *(float4*)qv = q0;
    *(float4*)(qv + 4) = q1;
    u16x8 pk;
    #pragma unroll
    for (int q = 0; q < 8; ++q) {
      // exp2(lrelu(e)) = max(2^el*2^er, 2^{.2el}*2^{.2er}) since PQ>=pq <=> e>=0
      const float v = fmaxf(Pv * Qv[q], pv * qv[q]);
      const int msk = ((int)(ab << (31 - q))) >> 31;  // adj bit -> 0 / -1
      pk[q] = f2bf(__builtin_bit_cast(float, __builtin_bit_cast(int, v) & msk));
    }
    const bf16x8 af = __builtin_bit_cast(bf16x8, pk);
    __builtin_amdgcn_s_setprio(1);
    accS = __builtin_amdgcn_mfma_f32_32x32x16_bf16(af, onesf, accS, 0, 0, 0);
    acc0 = __builtin_amdgcn_mfma_f32_32x32x16_bf16(
        af, __builtin_bit_cast(bf16x8, b0), acc0, 0, 0, 0);
    acc1 = __builtin_amdgcn_mfma_f32_32x32x16_bf16(
        af, __builtin_bit_cast(bf16x8, b1), acc1, 0, 0, 0);
    acc2 = __builtin_amdgcn_mfma_f32_32x32x16_bf16(
        af, __builtin_bit_cast(bf16x8, b2), acc2, 0, 0, 0);
    acc3 = __builtin_amdgcn_mfma_f32_32x32x16_bf16(
        af, __builtin_bit_cast(bf16x8, b3), acc3, 0, 0, 0);
    __builtin_amdgcn_s_setprio(0);
  };

  float4 Q0A, Q1A, q0A, q1A, Q0B, Q1B, q0B, q1B;
  u32 abA, abB;
  u16x8 b0A, b1A, b2A, b3A, b0B, b1B, b2B, b3B;
  loadP(0, Q0A, Q1A, q0A, q1A, abA, b0A, b1A, b2A, b3A);
  for (int pp = 0; pp < 32; ++pp) {
    loadP(2 * pp + 1, Q0B, Q1B, q0B, q1B, abB, b0B, b1B, b2B, b3B);
    computeP(Q0A, Q1A, q0A, q1A, abA, b0A, b1A, b2A, b3A);
    if (pp < 31)
      loadP(2 * pp + 2, Q0A, Q1A, q0A, q1A, abA, b0A, b1A, b2A, b3A);
    computeP(Q0B, Q1B, q0B, q1B, abB, b0B, b1B, b2B, b3B);
  }

  // ---- epilogue ----
  // S row-sums (all cols of accS identical; lanes l31==0 cover lh=0/1)
  if (l31 == 0) {
    #pragma unroll
    for (int reg = 0; reg < 16; ++reg) {
      const int crow = (reg & 3) + 8 * (reg >> 2) + 4 * lh;
      atomicAdd(&S_lds[rt * 32 + crow], accS[reg]);
    }
  }
  auto wr1 = [&](f32x16& a, int ct) {
    float* dst = red[rt] + ct * 1024 + lane * 4;
    #pragma unroll
    for (int q4 = 0; q4 < 4; ++q4)
      *(f32x4*)(dst + q4 * 256) =
          (f32x4){a[q4 * 4], a[q4 * 4 + 1], a[q4 * 4 + 2], a[q4 * 4 + 3]};
  };
  auto ad1 = [&](f32x16& a, int ct) {
    const float* s = red[rt] + ct * 1024 + lane * 4;
    #pragma unroll
    for (int q4 = 0; q4 < 4; ++q4) {
      const f32x4 v = *(const f32x4*)(s + q4 * 256);
      a[q4 * 4] += v[0];
      a[q4 * 4 + 1] += v[1];
      a[q4 * 4 + 2] += v[2];
      a[q4 * 4 + 3] += v[3];
    }
  };
  auto writeAcc = [&]() { wr1(acc0, 0); wr1(acc1, 1); wr1(acc2, 2); wr1(acc3, 3); };
  auto addAcc = [&]() { ad1(acc0, 0); ad1(acc1, 1); ad1(acc2, 2); ad1(acc3, 3); };

  __syncthreads();
  if (kkg == 1) writeAcc();
  __syncthreads();
  if (kkg == 0) addAcc();
  __syncthreads();
  if (kkg == 3) writeAcc();
  __syncthreads();
  if (kkg == 2) addAcc();
  __syncthreads();
  if (kkg == 2) writeAcc();
  __syncthreads();
  auto st1 = [&](f32x16& a, int ct) {
    const int col = ct * 32 + l31;
    const float bb = bias[col];
    #pragma unroll
    for (int reg = 0; reg < 16; ++reg) {
      const int crow = (reg & 3) + 8 * (reg >> 2) + 4 * lh;
      const int mrow = rt * 32 + crow;
      const float inv = 1.f / fmaxf(S_lds[mrow], 1e-12f);
      outp[(size_t)(i0 + (mrow & 15)) * (NH * DOUT) + (mrow >> 4) * DOUT + col] =
          a[reg] * inv + bb;
    }
  };
  if (kkg == 0) {
    addAcc();
    st1(acc0, 0);
    st1(acc1, 1);
    st1(acc2, 2);
    st1(acc3, 3);
  }
}

extern "C" void kernel_launch(void* const* d_in, const int* in_sizes, int n_in,
                              void* d_out, int out_size, void* d_ws, size_t ws_size,
                              hipStream_t stream) {
  const float* adj = (const float*)d_in[0];
  const float* x = (const float*)d_in[1];
  const float* W = (const float*)d_in[2];
  const float* alw = (const float*)d_in[3];
  const float* arw = (const float*)d_in[4];
  const float* bias = (const float*)d_in[5];
  float* out = (float*)d_out;
  char* ws = (char*)d_ws;
  u16x8* hTf = (u16x8*)ws;                                // 1 MB
  float* elP = (float*)(ws + 0x100000);                   // 64 KB
  float* elp = (float*)(ws + 0x110000);                   // 64 KB
  float* erQ = (float*)(ws + 0x120000);                   // 64 KB
  float* erq = (float*)(ws + 0x130000);                   // 64 KB
  unsigned char* adjB = (unsigned char*)(ws + 0x140000);  // 2 MB
  u16* wthi = (u16*)(ws + 0x340000);                      // 128 KB
  u16* wtlo = (u16*)(ws + 0x360000);                      // 128 KB

  pack_prep<<<2176, 256, 0, stream>>>(adj, (u64*)adjB, W, wthi, wtlo);
  hcompute<<<256, 512, 0, stream>>>(x, wthi, wtlo, alw, arw, hTf, elP, elp, erQ, erq);
  gat_main<<<256, 512, 0, stream>>>(adjB, (const u16x8*)hTf, elP, elp, erQ, erq,
                                    bias, out);
}